// Round 1
// baseline (2492.909 us; speedup 1.0000x reference)
//
#include <hip/hip_runtime.h>
#include <math.h>

#define BB 32
#define HH 128
#define WW 128
#define CC 64
#define MX 16
#define MY 16
#define NKX 32   // kx modes: 0..15 and 112..127

#define TWOPI 6.283185307179586f

// ws layout:
//   X1 / Z : float2 [B][16][H][C]  (X1: [b][ky][h][c]; later reused as Z: [b][h][ky][c])
//            = 32*16*128*64*8 = 33,554,432 bytes
//   X2     : float2 [B][NKX][MY][C] = 32*32*16*64*8 = 8,388,608 bytes  (kC in-place)
// total 41,943,040 bytes

// ---------------- kernel A: DFT over w (16 ky modes) ----------------
__global__ __launch_bounds__(256) void kA(const float* __restrict__ x, float2* __restrict__ X1) {
    __shared__ float xs[WW * CC];     // 32 KB
    __shared__ float2 tw[128];        // (cos, sin)(2*pi*k/128)
    int tid = threadIdx.x;
    int bh = blockIdx.x;              // b*128 + h
    if (tid < 128) {
        float s, c;
        sincosf(TWOPI * (float)tid * (1.0f / 128.0f), &s, &c);
        tw[tid] = make_float2(c, s);
    }
    const float* xp = x + (size_t)bh * (WW * CC);
    for (int i = tid * 4; i < WW * CC; i += 1024)
        *(float4*)&xs[i] = *(const float4*)&xp[i];
    __syncthreads();

    int cp = tid & 31;   // c pair
    int kp = tid >> 5;   // ky pair (0..7)
    int c0 = cp * 2;
    int ky0 = kp * 2;
    float a0r = 0, a0i = 0, a1r = 0, a1i = 0;   // ky0, c0 / c0+1
    float b0r = 0, b0i = 0, b1r = 0, b1i = 0;   // ky0+1
    #pragma unroll 8
    for (int w = 0; w < WW; ++w) {
        float2 xv = *(const float2*)&xs[w * CC + c0];
        float2 t0 = tw[(ky0 * w) & 127];
        float2 t1 = tw[((ky0 + 1) * w) & 127];
        // x * e^{-i theta} = (x*cos, -x*sin)
        a0r += xv.x * t0.x;  a0i -= xv.x * t0.y;
        a1r += xv.y * t0.x;  a1i -= xv.y * t0.y;
        b0r += xv.x * t1.x;  b0i -= xv.x * t1.y;
        b1r += xv.y * t1.x;  b1i -= xv.y * t1.y;
    }
    int b = bh >> 7, h = bh & 127;
    size_t base = (size_t)b * 16;
    float4 v0 = make_float4(a0r, a0i, a1r, a1i);
    float4 v1 = make_float4(b0r, b0i, b1r, b1i);
    *(float4*)&X1[((base + ky0) * HH + h) * CC + c0] = v0;
    *(float4*)&X1[((base + ky0 + 1) * HH + h) * CC + c0] = v1;
}

// ---------------- kernel B: DFT over h (32 kx modes) ----------------
__global__ __launch_bounds__(256) void kB(const float2* __restrict__ X1, float2* __restrict__ X2) {
    __shared__ float2 tw[128];
    int tid = threadIdx.x;
    if (tid < 128) {
        float s, c;
        sincosf(TWOPI * (float)tid * (1.0f / 128.0f), &s, &c);
        tw[tid] = make_float2(c, s);
    }
    __syncthreads();
    int blk = blockIdx.x;             // b*16 + ky
    int b = blk >> 4, ky = blk & 15;
    const float2* p = X1 + (size_t)blk * (HH * CC);   // [h][c]
    int c = tid & 63, kg = tid >> 6;  // kg 0..3 -> kxi = kg*8 + j
    float xr[8] = {0, 0, 0, 0, 0, 0, 0, 0};
    float xi[8] = {0, 0, 0, 0, 0, 0, 0, 0};
    #pragma unroll 4
    for (int h = 0; h < HH; ++h) {
        float2 v = p[h * CC + c];
        #pragma unroll
        for (int j = 0; j < 8; ++j) {
            int kxi = kg * 8 + j;
            int kx = (kxi < 16) ? kxi : (96 + kxi);
            float2 t = tw[(kx * h) & 127];
            // (vr + i vi) * (cos - i sin)
            xr[j] += v.x * t.x + v.y * t.y;
            xi[j] += v.y * t.x - v.x * t.y;
        }
    }
    #pragma unroll
    for (int j = 0; j < 8; ++j) {
        int kxi = kg * 8 + j;
        X2[(((size_t)b * NKX + kxi) * MY + ky) * CC + c] = make_float2(xr[j], xi[j]);
    }
}

// ---------------- kernel C: complex channel mix (in-place on X2) ----------------
__global__ __launch_bounds__(256) void kC(const float* __restrict__ w1r, const float* __restrict__ w1i,
                                          const float* __restrict__ w2r, const float* __restrict__ w2i,
                                          float2* __restrict__ X2) {
    __shared__ float swr[CC * CC];    // 16 KB [i][o]
    __shared__ float swi[CC * CC];    // 16 KB
    __shared__ float2 xsh[BB * CC];   // 16 KB [b][i]
    int tid = threadIdx.x;
    int blk = blockIdx.x;             // kxi*16 + ky
    int kxi = blk >> 4, ky = blk & 15;
    const float* wr = (kxi < 16) ? w1r : w2r;
    const float* wi = (kxi < 16) ? w1i : w2i;
    int wx = (kxi < 16) ? kxi : (kxi - 16);
    size_t woff = ((size_t)wx * MY + ky) * (CC * CC);
    for (int i = tid * 4; i < CC * CC; i += 1024) {
        *(float4*)&swr[i] = *(const float4*)&wr[woff + i];
        *(float4*)&swi[i] = *(const float4*)&wi[woff + i];
    }
    for (int i = tid; i < BB * CC; i += 256) {
        int bb = i >> 6, cc2 = i & 63;
        xsh[i] = X2[(((size_t)bb * NKX + kxi) * MY + ky) * CC + cc2];
    }
    __syncthreads();
    int o = tid & 63, bg = tid >> 6;
    float orr[8] = {0, 0, 0, 0, 0, 0, 0, 0};
    float oii[8] = {0, 0, 0, 0, 0, 0, 0, 0};
    for (int i = 0; i < CC; ++i) {
        float wrv = swr[i * CC + o], wiv = swi[i * CC + o];
        #pragma unroll
        for (int j = 0; j < 8; ++j) {
            float2 xv = xsh[(bg * 8 + j) * CC + i];
            orr[j] += xv.x * wrv - xv.y * wiv;
            oii[j] += xv.x * wiv + xv.y * wrv;
        }
    }
    #pragma unroll
    for (int j = 0; j < 8; ++j) {
        int bb = bg * 8 + j;
        X2[(((size_t)bb * NKX + kxi) * MY + ky) * CC + o] = make_float2(orr[j], oii[j]);
    }
}

// ---------------- kernel D: inverse DFT over kx ----------------
__global__ __launch_bounds__(256) void kD(const float2* __restrict__ G, float2* __restrict__ Z) {
    __shared__ float2 gs[NKX * CC];   // 16 KB
    __shared__ float2 tw[128];
    int tid = threadIdx.x;
    if (tid < 128) {
        float s, c;
        sincosf(TWOPI * (float)tid * (1.0f / 128.0f), &s, &c);
        tw[tid] = make_float2(c, s);
    }
    int blk = blockIdx.x;             // b*16 + ky
    int b = blk >> 4, ky = blk & 15;
    for (int i = tid; i < NKX * CC; i += 256) {
        int kxi = i >> 6, cc2 = i & 63;
        gs[i] = G[(((size_t)b * NKX + kxi) * MY + ky) * CC + cc2];
    }
    __syncthreads();
    int c = tid & 63, hg = tid >> 6;  // hg 0..3
    for (int pass = 0; pass < 4; ++pass) {
        int h0 = hg * 32 + pass * 8;
        float zr[8] = {0, 0, 0, 0, 0, 0, 0, 0};
        float zi[8] = {0, 0, 0, 0, 0, 0, 0, 0};
        for (int kxi = 0; kxi < NKX; ++kxi) {
            int kx = (kxi < 16) ? kxi : (96 + kxi);
            float2 v = gs[kxi * CC + c];
            #pragma unroll
            for (int j = 0; j < 8; ++j) {
                float2 t = tw[(kx * (h0 + j)) & 127];
                // (vr + i vi) * (cos + i sin)
                zr[j] += v.x * t.x - v.y * t.y;
                zi[j] += v.x * t.y + v.y * t.x;
            }
        }
        #pragma unroll
        for (int j = 0; j < 8; ++j) {
            Z[(((size_t)b * HH + (h0 + j)) * MY + ky) * CC + c] = make_float2(zr[j], zi[j]);
        }
    }
}

// ---------------- kernel E: inverse over ky + dense + residual + GELU ----------------
__global__ __launch_bounds__(256, 2) void kE(const float* __restrict__ x, const float2* __restrict__ Z,
                                             const float* __restrict__ K, const float* __restrict__ bias,
                                             float* __restrict__ out) {
    __shared__ float xs[WW * CC];     // 32 KB
    __shared__ float ks[CC * CC];     // 16 KB [i][o]
    __shared__ float2 zs[MY * CC];    // 8 KB
    __shared__ float2 tw[128];        // 1 KB
    __shared__ float bs[CC];
    int tid = threadIdx.x;
    int bh = blockIdx.x;              // b*128 + h
    if (tid < 128) {
        float s, c;
        sincosf(TWOPI * (float)tid * (1.0f / 128.0f), &s, &c);
        tw[tid] = make_float2(c, s);
    }
    if (tid < CC) bs[tid] = bias[tid];
    const float* xp = x + (size_t)bh * (WW * CC);
    for (int i = tid * 4; i < WW * CC; i += 1024)
        *(float4*)&xs[i] = *(const float4*)&xp[i];
    for (int i = tid * 4; i < CC * CC; i += 1024)
        *(float4*)&ks[i] = *(const float4*)&K[i];
    const float2* zp = Z + (size_t)bh * (MY * CC);
    for (int i = tid; i < MY * CC; i += 256)
        zs[i] = zp[i];
    __syncthreads();

    int c = tid & 63, wg = tid >> 6;
    // dense kernel column K[:, c] into registers
    float kreg[CC];
    #pragma unroll
    for (int i = 0; i < CC; ++i) kreg[i] = ks[i * CC + c];
    // spectral row Z[bh, :, c] into registers, pre-scaled
    const float inv = 1.0f / 16384.0f;
    float zrr[MY], zii[MY];
    #pragma unroll
    for (int ky = 0; ky < MY; ++ky) {
        float2 zv = zs[ky * CC + c];
        float s = ((ky == 0) ? 1.0f : 2.0f) * inv;
        zrr[ky] = zv.x * s;
        zii[ky] = zv.y * s;
    }
    for (int pass = 0; pass < 4; ++pass) {
        int w0 = wg * 32 + pass * 8;
        float acc[8];
        #pragma unroll
        for (int j = 0; j < 8; ++j) acc[j] = bs[c];
        #pragma unroll
        for (int i = 0; i < CC; i += 4) {
            float k0 = kreg[i], k1 = kreg[i + 1], k2 = kreg[i + 2], k3 = kreg[i + 3];
            #pragma unroll
            for (int j = 0; j < 8; ++j) {
                float4 xv = *(const float4*)&xs[(w0 + j) * CC + i];
                acc[j] += xv.x * k0 + xv.y * k1 + xv.z * k2 + xv.w * k3;
            }
        }
        #pragma unroll
        for (int j = 0; j < 8; ++j) {
            int w = w0 + j;
            float spec = 0.0f;
            #pragma unroll
            for (int ky = 0; ky < MY; ++ky) {
                float2 t = tw[(ky * w) & 127];
                spec += zrr[ky] * t.x - zii[ky] * t.y;
            }
            float u = xs[w * CC + c] + spec + acc[j];
            float g = 0.5f * u * (1.0f + tanhf(0.7978845608028654f * (u + 0.044715f * u * u * u)));
            out[(size_t)bh * (WW * CC) + (size_t)w * CC + c] = g;
        }
    }
}

extern "C" void kernel_launch(void* const* d_in, const int* in_sizes, int n_in,
                              void* d_out, int out_size, void* d_ws, size_t ws_size,
                              hipStream_t stream) {
    const float* x   = (const float*)d_in[0];
    const float* w1r = (const float*)d_in[1];
    const float* w1i = (const float*)d_in[2];
    const float* w2r = (const float*)d_in[3];
    const float* w2i = (const float*)d_in[4];
    const float* dk  = (const float*)d_in[5];
    const float* db  = (const float*)d_in[6];
    float* out = (float*)d_out;

    float2* X1 = (float2*)d_ws;                               // 33,554,432 B (also Z)
    float2* X2 = (float2*)((char*)d_ws + 33554432);           //  8,388,608 B

    kA<<<BB * HH, 256, 0, stream>>>(x, X1);
    kB<<<BB * MY, 256, 0, stream>>>(X1, X2);
    kC<<<NKX * MY, 256, 0, stream>>>(w1r, w1i, w2r, w2i, X2);
    kD<<<BB * MY, 256, 0, stream>>>(X2, X1);                  // Z reuses X1 buffer
    kE<<<BB * HH, 256, 0, stream>>>(x, X1, dk, db, out);
}

// Round 2
// 443.988 us; speedup vs baseline: 5.6148x; 5.6148x over previous
//
#include <hip/hip_runtime.h>
#include <math.h>

#define BB 32
#define HH 128
#define WW 128
#define CC 64
#define MX 16
#define MY 16
#define NKX 32   // kx modes: 0..15 and 112..127

#define TWOPI 6.283185307179586f

typedef __attribute__((ext_vector_type(8))) short bf16x8;
typedef __attribute__((ext_vector_type(4))) float f32x4;

__device__ inline unsigned short f2bf(float f) {
    union { float f; unsigned u; } v; v.f = f;
    unsigned r = v.u + 0x7FFFu + ((v.u >> 16) & 1u);   // RTNE
    return (unsigned short)(r >> 16);
}

// ws layout:
//   X1 / Z : float2 [B][16][H][C]  (X1: [b][ky][h][c]; later reused as Z: [b][h][ky][c])
//            = 33,554,432 bytes
//   X2     : float2 [B][NKX][MY][C] = 8,388,608 bytes  (kC in-place)

// ---------------- kernel A: DFT over w (16 ky modes) ----------------
__global__ __launch_bounds__(256) void kA(const float* __restrict__ x, float2* __restrict__ X1) {
    __shared__ float xs[WW * CC];     // 32 KB
    __shared__ float2 tw[128];        // (cos, sin)(2*pi*k/128)
    int tid = threadIdx.x;
    int bh = blockIdx.x;              // b*128 + h
    if (tid < 128) {
        float s, c;
        sincosf(TWOPI * (float)tid * (1.0f / 128.0f), &s, &c);
        tw[tid] = make_float2(c, s);
    }
    const float* xp = x + (size_t)bh * (WW * CC);
    for (int i = tid * 4; i < WW * CC; i += 1024)
        *(float4*)&xs[i] = *(const float4*)&xp[i];
    __syncthreads();

    int cp = tid & 31;   // c pair
    int kp = tid >> 5;   // ky pair (0..7)
    int c0 = cp * 2;
    int ky0 = kp * 2;
    float a0r = 0, a0i = 0, a1r = 0, a1i = 0;
    float b0r = 0, b0i = 0, b1r = 0, b1i = 0;
    #pragma unroll 8
    for (int w = 0; w < WW; ++w) {
        float2 xv = *(const float2*)&xs[w * CC + c0];
        float2 t0 = tw[(ky0 * w) & 127];
        float2 t1 = tw[((ky0 + 1) * w) & 127];
        a0r += xv.x * t0.x;  a0i -= xv.x * t0.y;
        a1r += xv.y * t0.x;  a1i -= xv.y * t0.y;
        b0r += xv.x * t1.x;  b0i -= xv.x * t1.y;
        b1r += xv.y * t1.x;  b1i -= xv.y * t1.y;
    }
    int b = bh >> 7, h = bh & 127;
    size_t base = (size_t)b * 16;
    float4 v0 = make_float4(a0r, a0i, a1r, a1i);
    float4 v1 = make_float4(b0r, b0i, b1r, b1i);
    *(float4*)&X1[((base + ky0) * HH + h) * CC + c0] = v0;
    *(float4*)&X1[((base + ky0 + 1) * HH + h) * CC + c0] = v1;
}

// ---------------- kernel B: DFT over h (32 kx modes) ----------------
__global__ __launch_bounds__(256) void kB(const float2* __restrict__ X1, float2* __restrict__ X2) {
    __shared__ float2 tw[128];
    int tid = threadIdx.x;
    if (tid < 128) {
        float s, c;
        sincosf(TWOPI * (float)tid * (1.0f / 128.0f), &s, &c);
        tw[tid] = make_float2(c, s);
    }
    __syncthreads();
    int blk = blockIdx.x;             // b*16 + ky
    int b = blk >> 4, ky = blk & 15;
    const float2* p = X1 + (size_t)blk * (HH * CC);   // [h][c]
    int c = tid & 63, kg = tid >> 6;
    float xr[8] = {0, 0, 0, 0, 0, 0, 0, 0};
    float xi[8] = {0, 0, 0, 0, 0, 0, 0, 0};
    #pragma unroll 4
    for (int h = 0; h < HH; ++h) {
        float2 v = p[h * CC + c];
        #pragma unroll
        for (int j = 0; j < 8; ++j) {
            int kxi = kg * 8 + j;
            int kx = (kxi < 16) ? kxi : (96 + kxi);
            float2 t = tw[(kx * h) & 127];
            xr[j] += v.x * t.x + v.y * t.y;
            xi[j] += v.y * t.x - v.x * t.y;
        }
    }
    #pragma unroll
    for (int j = 0; j < 8; ++j) {
        int kxi = kg * 8 + j;
        X2[(((size_t)b * NKX + kxi) * MY + ky) * CC + c] = make_float2(xr[j], xi[j]);
    }
}

// ---------------- kernel C: complex channel mix (in-place on X2) ----------------
__global__ __launch_bounds__(256) void kC(const float* __restrict__ w1r, const float* __restrict__ w1i,
                                          const float* __restrict__ w2r, const float* __restrict__ w2i,
                                          float2* __restrict__ X2) {
    __shared__ float swr[CC * CC];
    __shared__ float swi[CC * CC];
    __shared__ float2 xsh[BB * CC];
    int tid = threadIdx.x;
    int blk = blockIdx.x;             // kxi*16 + ky
    int kxi = blk >> 4, ky = blk & 15;
    const float* wr = (kxi < 16) ? w1r : w2r;
    const float* wi = (kxi < 16) ? w1i : w2i;
    int wx = (kxi < 16) ? kxi : (kxi - 16);
    size_t woff = ((size_t)wx * MY + ky) * (CC * CC);
    for (int i = tid * 4; i < CC * CC; i += 1024) {
        *(float4*)&swr[i] = *(const float4*)&wr[woff + i];
        *(float4*)&swi[i] = *(const float4*)&wi[woff + i];
    }
    for (int i = tid; i < BB * CC; i += 256) {
        int bb = i >> 6, cc2 = i & 63;
        xsh[i] = X2[(((size_t)bb * NKX + kxi) * MY + ky) * CC + cc2];
    }
    __syncthreads();
    int o = tid & 63, bg = tid >> 6;
    float orr[8] = {0, 0, 0, 0, 0, 0, 0, 0};
    float oii[8] = {0, 0, 0, 0, 0, 0, 0, 0};
    for (int i = 0; i < CC; ++i) {
        float wrv = swr[i * CC + o], wiv = swi[i * CC + o];
        #pragma unroll
        for (int j = 0; j < 8; ++j) {
            float2 xv = xsh[(bg * 8 + j) * CC + i];
            orr[j] += xv.x * wrv - xv.y * wiv;
            oii[j] += xv.x * wiv + xv.y * wrv;
        }
    }
    #pragma unroll
    for (int j = 0; j < 8; ++j) {
        int bb = bg * 8 + j;
        X2[(((size_t)bb * NKX + kxi) * MY + ky) * CC + o] = make_float2(orr[j], oii[j]);
    }
}

// ---------------- kernel D: inverse DFT over kx ----------------
__global__ __launch_bounds__(256) void kD(const float2* __restrict__ G, float2* __restrict__ Z) {
    __shared__ float2 gs[NKX * CC];
    __shared__ float2 tw[128];
    int tid = threadIdx.x;
    if (tid < 128) {
        float s, c;
        sincosf(TWOPI * (float)tid * (1.0f / 128.0f), &s, &c);
        tw[tid] = make_float2(c, s);
    }
    int blk = blockIdx.x;             // b*16 + ky
    int b = blk >> 4, ky = blk & 15;
    for (int i = tid; i < NKX * CC; i += 256) {
        int kxi = i >> 6, cc2 = i & 63;
        gs[i] = G[(((size_t)b * NKX + kxi) * MY + ky) * CC + cc2];
    }
    __syncthreads();
    int c = tid & 63, hg = tid >> 6;
    for (int pass = 0; pass < 4; ++pass) {
        int h0 = hg * 32 + pass * 8;
        float zr[8] = {0, 0, 0, 0, 0, 0, 0, 0};
        float zi[8] = {0, 0, 0, 0, 0, 0, 0, 0};
        for (int kxi = 0; kxi < NKX; ++kxi) {
            int kx = (kxi < 16) ? kxi : (96 + kxi);
            float2 v = gs[kxi * CC + c];
            #pragma unroll
            for (int j = 0; j < 8; ++j) {
                float2 t = tw[(kx * (h0 + j)) & 127];
                zr[j] += v.x * t.x - v.y * t.y;
                zi[j] += v.x * t.y + v.y * t.x;
            }
        }
        #pragma unroll
        for (int j = 0; j < 8; ++j) {
            Z[(((size_t)b * HH + (h0 + j)) * MY + ky) * CC + c] = make_float2(zr[j], zi[j]);
        }
    }
}

// ---------------- kernel E: MFMA GEMM  out = GELU(x + [x|T]@[K;Z] + bias) ----------------
// A = [128 rows(w) x 96 cols(k)]: k<64 -> x[w][k] ; k=64+2ky -> cos*s ; k=64+2ky+1 -> -sin*s
// B = [96 x 64 cols(c)]:          k<64 -> K[k][c] ; k=64+2ky -> zr[ky][c] ; +1 -> zi[ky][c]
// Fragments stored in fragment-linear LDS: frag[tile][kstep][lane][8 bf16].
__global__ __launch_bounds__(256, 2) void kE(const float* __restrict__ x, const float2* __restrict__ Z,
                                             const float* __restrict__ K, const float* __restrict__ bias,
                                             float* __restrict__ out) {
    __shared__ float xs[WW * CC];               // 32 KB fp32 (residual + A source)
    __shared__ short Afrag[8 * 3 * 64 * 8];     // 24 KB
    __shared__ short Bfrag[4 * 3 * 64 * 8];     // 12 KB
    __shared__ float2 tw[128];                  // 1 KB
    int tid = threadIdx.x;
    int bh = blockIdx.x;                        // b*128 + h
    if (tid < 128) {
        float s, c;
        sincosf(TWOPI * (float)tid * (1.0f / 128.0f), &s, &c);
        tw[tid] = make_float2(c, s);
    }
    const float* xp = x + (size_t)bh * (WW * CC);
    for (int i = tid * 4; i < WW * CC; i += 1024)
        *(float4*)&xs[i] = *(const float4*)&xp[i];
    __syncthreads();

    const float inv = 1.0f / 16384.0f;
    // ---- build A fragments (1536 slots, 6 per thread) ----
    #pragma unroll
    for (int s = 0; s < 6; ++s) {
        int slot = tid + s * 256;
        int l = slot & 63;
        int ks = (slot >> 6) % 3;
        int tm = slot / 192;
        int q = l >> 4, r = l & 15;
        int row = tm * 16 + r;
        short v[8];
        if (ks < 2) {
            int k0 = ks * 32 + q * 8;
            #pragma unroll
            for (int e = 0; e < 8; ++e) v[e] = (short)f2bf(xs[row * CC + k0 + e]);
        } else {
            #pragma unroll
            for (int e = 0; e < 8; ++e) {
                int ky = 4 * q + (e >> 1);
                float sc = ((ky == 0) ? 1.0f : 2.0f) * inv;
                float2 t = tw[(ky * row) & 127];
                float val = (e & 1) ? (-t.y * sc) : (t.x * sc);
                v[e] = (short)f2bf(val);
            }
        }
        *(bf16x8*)&Afrag[slot * 8] = *(const bf16x8*)v;
    }
    // ---- build B fragments (768 slots, 3 per thread) ----
    const float2* zp = Z + (size_t)bh * (MY * CC);
    #pragma unroll
    for (int s = 0; s < 3; ++s) {
        int slot = tid + s * 256;
        int l = slot & 63;
        int ks = (slot >> 6) % 3;
        int nt = slot / 192;
        int q = l >> 4, r = l & 15;
        int col = nt * 16 + r;
        short v[8];
        if (ks < 2) {
            #pragma unroll
            for (int e = 0; e < 8; ++e) {
                int k = ks * 32 + q * 8 + e;
                v[e] = (short)f2bf(K[k * CC + col]);
            }
        } else {
            #pragma unroll
            for (int e = 0; e < 8; ++e) {
                int kp = q * 8 + e;
                int ky = kp >> 1;
                float2 zv = zp[ky * CC + col];
                v[e] = (short)f2bf((kp & 1) ? zv.y : zv.x);
            }
        }
        *(bf16x8*)&Bfrag[slot * 8] = *(const bf16x8*)v;
    }
    __syncthreads();

    // ---- MFMA: each wave owns 2 M-tiles x 4 N-tiles ----
    int lane = tid & 63;
    int wv = tid >> 6;
    int q = lane >> 4, r = lane & 15;
    #pragma unroll
    for (int nt = 0; nt < 4; ++nt) {
        #pragma unroll
        for (int t2 = 0; t2 < 2; ++t2) {
            int tm = wv * 2 + t2;
            f32x4 acc = {0.f, 0.f, 0.f, 0.f};
            #pragma unroll
            for (int ks = 0; ks < 3; ++ks) {
                bf16x8 a = *(const bf16x8*)&Afrag[((tm * 3 + ks) * 64 + lane) * 8];
                bf16x8 b = *(const bf16x8*)&Bfrag[((nt * 3 + ks) * 64 + lane) * 8];
                acc = __builtin_amdgcn_mfma_f32_16x16x32_bf16(a, b, acc, 0, 0, 0);
            }
            int c = nt * 16 + r;
            float bsv = bias[c];
            #pragma unroll
            for (int j = 0; j < 4; ++j) {
                int w = tm * 16 + q * 4 + j;
                float u = acc[j] + xs[w * CC + c] + bsv;
                float t = u + 0.044715f * u * u * u;
                float e = __expf(-1.5957691216057308f * t);   // gelu = u * sigmoid(2*0.79788456*t)
                out[(size_t)bh * (WW * CC) + w * CC + c] = u / (1.0f + e);
            }
        }
    }
}

extern "C" void kernel_launch(void* const* d_in, const int* in_sizes, int n_in,
                              void* d_out, int out_size, void* d_ws, size_t ws_size,
                              hipStream_t stream) {
    const float* x   = (const float*)d_in[0];
    const float* w1r = (const float*)d_in[1];
    const float* w1i = (const float*)d_in[2];
    const float* w2r = (const float*)d_in[3];
    const float* w2i = (const float*)d_in[4];
    const float* dk  = (const float*)d_in[5];
    const float* db  = (const float*)d_in[6];
    float* out = (float*)d_out;

    float2* X1 = (float2*)d_ws;                               // 33,554,432 B (also Z)
    float2* X2 = (float2*)((char*)d_ws + 33554432);           //  8,388,608 B

    kA<<<BB * HH, 256, 0, stream>>>(x, X1);
    kB<<<BB * MY, 256, 0, stream>>>(X1, X2);
    kC<<<NKX * MY, 256, 0, stream>>>(w1r, w1i, w2r, w2i, X2);
    kD<<<BB * MY, 256, 0, stream>>>(X2, X1);                  // Z reuses X1 buffer
    kE<<<BB * HH, 256, 0, stream>>>(x, X1, dk, db, out);
}

// Round 3
// 319.449 us; speedup vs baseline: 7.8038x; 1.3899x over previous
//
#include <hip/hip_runtime.h>
#include <math.h>

#define BB 32
#define HH 128
#define WW 128
#define CC 64
#define MX 16
#define MY 16
#define NKX 32   // kx modes: 0..15 and 112..127

#define TWOPI 6.283185307179586f

typedef __attribute__((ext_vector_type(8))) short bf16x8;
typedef __attribute__((ext_vector_type(4))) float f32x4;

__device__ inline unsigned short f2bf(float f) {
    union { float f; unsigned u; } v; v.f = f;
    unsigned r = v.u + 0x7FFFu + ((v.u >> 16) & 1u);   // RTNE
    return (unsigned short)(r >> 16);
}

// ws layout (all bf16 = unsigned short):
//   X1 [32][16][128][2][64]  : 8,388,608 elems  (per (b,ky): row k=2h+ri, col c)
//   X2 [32][32][16][128]     : 2,097,152 elems  (last dim = 2c+ri)
//   G  [32][32][16][128]     : 2,097,152 elems  (last dim = 2o+ro)
//   Z  [32][128][16][128]    : 8,388,608 elems  (last dim = 2c+ri)
// total 41,943,040 bytes

// Fragment convention (verified by round-2 kE):
//   A-frag: lane l=(q=l>>4, r=l&15) holds A[row=r][k=q*8+e], e=0..7
//   B-frag: lane l holds B[k=q*8+e][col=r]
//   C/D   : acc[j] -> row=q*4+j, col=r

// ---------------- kA: DFT over w as GEMM [32 x 128] @ [128 x 64] per (b,h) ----------------
__global__ __launch_bounds__(256) void kA(const float* __restrict__ x, unsigned short* __restrict__ X1) {
    __shared__ float2 tw[128];
    __shared__ short Af[2 * 4 * 64 * 8];   // 8 KB  [mt][ks][lane][8]
    int tid = threadIdx.x;
    int bh = blockIdx.x;                   // b*128 + h
    if (tid < 128) {
        float s, c;
        sincosf(TWOPI * (float)tid * (1.0f / 128.0f), &s, &c);
        tw[tid] = make_float2(c, s);
    }
    __syncthreads();
    // A[row=2ky+ri][w] : ri==0 -> cos(2pi ky w/128), ri==1 -> -sin
    #pragma unroll
    for (int s = 0; s < 2; ++s) {
        int slot = tid + s * 256;          // 512 slots
        int l = slot & 63, ks = (slot >> 6) & 3, mt = slot >> 8;
        int q = l >> 4, r = l & 15;
        int row = mt * 16 + r;
        int ky = row >> 1, ri = row & 1;
        int k0 = ks * 32 + q * 8;
        short v[8];
        #pragma unroll
        for (int e = 0; e < 8; ++e) {
            float2 t = tw[(ky * (k0 + e)) & 127];
            v[e] = (short)f2bf(ri ? -t.y : t.x);
        }
        *(bf16x8*)&Af[slot * 8] = *(const bf16x8*)v;
    }
    __syncthreads();

    int lane = tid & 63, wid = tid >> 6;
    int q = lane >> 4, r = lane & 15;
    int nt = wid;                          // wave owns one 16-col tile
    const float* xp = x + (size_t)bh * (WW * CC);
    bf16x8 bf[4];
    #pragma unroll
    for (int ks = 0; ks < 4; ++ks) {
        short v[8];
        #pragma unroll
        for (int e = 0; e < 8; ++e)
            v[e] = (short)f2bf(xp[(ks * 32 + q * 8 + e) * CC + nt * 16 + r]);
        bf[ks] = *(const bf16x8*)v;
    }
    f32x4 acc0 = {0.f, 0.f, 0.f, 0.f}, acc1 = {0.f, 0.f, 0.f, 0.f};
    #pragma unroll
    for (int ks = 0; ks < 4; ++ks) {
        bf16x8 a0 = *(const bf16x8*)&Af[((0 * 4 + ks) * 64 + lane) * 8];
        bf16x8 a1 = *(const bf16x8*)&Af[((1 * 4 + ks) * 64 + lane) * 8];
        acc0 = __builtin_amdgcn_mfma_f32_16x16x32_bf16(a0, bf[ks], acc0, 0, 0, 0);
        acc1 = __builtin_amdgcn_mfma_f32_16x16x32_bf16(a1, bf[ks], acc1, 0, 0, 0);
    }
    int b = bh >> 7, h = bh & 127;
    int c = nt * 16 + r;
    #pragma unroll
    for (int j = 0; j < 4; ++j) {
        int m0 = q * 4 + j;
        X1[(((size_t)b * 16 + (m0 >> 1)) * 128 + h) * 128 + (m0 & 1) * 64 + c] = f2bf(acc0[j]);
        int m1 = 16 + m0;
        X1[(((size_t)b * 16 + (m1 >> 1)) * 128 + h) * 128 + (m1 & 1) * 64 + c] = f2bf(acc1[j]);
    }
}

// ---------------- kB: DFT over h as GEMM [64 x 256] @ [256 x 64] per (b,ky) ----------------
__global__ __launch_bounds__(256) void kB(const unsigned short* __restrict__ X1, unsigned short* __restrict__ X2) {
    __shared__ float2 tw[128];
    __shared__ short Af[4 * 8 * 64 * 8];   // 32 KB  [mt][ks][lane][8]
    int tid = threadIdx.x;
    if (tid < 128) {
        float s, c;
        sincosf(TWOPI * (float)tid * (1.0f / 128.0f), &s, &c);
        tw[tid] = make_float2(c, s);
    }
    __syncthreads();
    // A[row=2kxi+rr][k=2h+ri]: rr0: (cos, sin) ; rr1: (-sin, cos)
    #pragma unroll
    for (int s = 0; s < 8; ++s) {
        int slot = tid + s * 256;          // 2048 slots
        int l = slot & 63, ks = (slot >> 6) & 7, mt = slot >> 9;
        int q = l >> 4, r = l & 15;
        int row = mt * 16 + r;
        int kxi = row >> 1, rr = row & 1;
        int kx = (kxi < 16) ? kxi : (96 + kxi);
        int k0 = ks * 32 + q * 8;
        short v[8];
        #pragma unroll
        for (int e = 0; e < 8; ++e) {
            int k = k0 + e;
            int h = k >> 1, ri = k & 1;
            float2 t = tw[(kx * h) & 127];
            float val = (rr == 0) ? (ri == 0 ? t.x : t.y) : (ri == 0 ? -t.y : t.x);
            v[e] = (short)f2bf(val);
        }
        *(bf16x8*)&Af[slot * 8] = *(const bf16x8*)v;
    }
    __syncthreads();

    int blk = blockIdx.x;                  // b*16 + ky
    int b = blk >> 4, ky = blk & 15;
    const unsigned short* p = X1 + ((size_t)b * 16 + ky) * 16384;   // [k=2h+ri][c]
    int lane = tid & 63, wid = tid >> 6;
    int q = lane >> 4, r = lane & 15;
    int col = wid * 16 + r;
    bf16x8 bf[8];
    #pragma unroll
    for (int ks = 0; ks < 8; ++ks) {
        short v[8];
        #pragma unroll
        for (int e = 0; e < 8; ++e)
            v[e] = (short)p[(ks * 32 + q * 8 + e) * 64 + col];
        bf[ks] = *(const bf16x8*)v;
    }
    f32x4 acc[4] = {{0.f,0.f,0.f,0.f},{0.f,0.f,0.f,0.f},{0.f,0.f,0.f,0.f},{0.f,0.f,0.f,0.f}};
    #pragma unroll
    for (int ks = 0; ks < 8; ++ks) {
        #pragma unroll
        for (int mt = 0; mt < 4; ++mt) {
            bf16x8 a = *(const bf16x8*)&Af[((mt * 8 + ks) * 64 + lane) * 8];
            acc[mt] = __builtin_amdgcn_mfma_f32_16x16x32_bf16(a, bf[ks], acc[mt], 0, 0, 0);
        }
    }
    #pragma unroll
    for (int mt = 0; mt < 4; ++mt) {
        #pragma unroll
        for (int j = 0; j < 4; ++j) {
            int m = mt * 16 + q * 4 + j;
            int kxi = m >> 1, rr = m & 1;
            X2[(((size_t)b * NKX + kxi) * 16 + ky) * 128 + 2 * col + rr] = f2bf(acc[mt][j]);
        }
    }
}

// ---------------- kC: channel mix as GEMM [32 x 128] @ [128 x 128] per mode ----------------
__global__ __launch_bounds__(256) void kC(const float* __restrict__ w1r, const float* __restrict__ w1i,
                                          const float* __restrict__ w2r, const float* __restrict__ w2i,
                                          const unsigned short* __restrict__ X2, unsigned short* __restrict__ G) {
    __shared__ float wsr[CC * CC];    // 16 KB
    __shared__ float wsi[CC * CC];    // 16 KB
    int tid = threadIdx.x;
    int blk = blockIdx.x;             // kxi*16 + ky
    int kxi = blk >> 4, ky = blk & 15;
    const float* wr = (kxi < 16) ? w1r : w2r;
    const float* wi = (kxi < 16) ? w1i : w2i;
    int wx = (kxi < 16) ? kxi : (kxi - 16);
    size_t woff = ((size_t)wx * MY + ky) * (CC * CC);
    for (int i = tid * 4; i < CC * CC; i += 1024) {
        *(float4*)&wsr[i] = *(const float4*)&wr[woff + i];
        *(float4*)&wsi[i] = *(const float4*)&wi[woff + i];
    }
    __syncthreads();

    int lane = tid & 63, wid = tid >> 6;
    int q = lane >> 4, r = lane & 15;
    // A-frags direct from X2 (contiguous 16B per lane): A[row=b][k=2i+ri]
    bf16x8 af[2][4];
    #pragma unroll
    for (int mt = 0; mt < 2; ++mt) {
        int b = mt * 16 + r;
        #pragma unroll
        for (int ks = 0; ks < 4; ++ks)
            af[mt][ks] = *(const bf16x8*)&X2[(((size_t)b * NKX + kxi) * 16 + ky) * 128 + ks * 32 + q * 8];
    }
    // B-frags: B[k=2i+ri][n=2o+ro] = ri0: (wr, wi) ; ri1: (-wi, wr)
    bf16x8 bfr[2][4];
    #pragma unroll
    for (int t = 0; t < 2; ++t) {
        int n = (wid * 2 + t) * 16 + r;
        int o = n >> 1, ro = n & 1;
        #pragma unroll
        for (int ks = 0; ks < 4; ++ks) {
            short v[8];
            #pragma unroll
            for (int e = 0; e < 8; ++e) {
                int k = ks * 32 + q * 8 + e;
                int i = k >> 1, ri = k & 1;
                float val = (ri == 0) ? (ro ? wsi[i * 64 + o] : wsr[i * 64 + o])
                                      : (ro ? wsr[i * 64 + o] : -wsi[i * 64 + o]);
                v[e] = (short)f2bf(val);
            }
            bfr[t][ks] = *(const bf16x8*)v;
        }
    }
    f32x4 acc[2][2] = {{{0.f,0.f,0.f,0.f},{0.f,0.f,0.f,0.f}},{{0.f,0.f,0.f,0.f},{0.f,0.f,0.f,0.f}}};
    #pragma unroll
    for (int ks = 0; ks < 4; ++ks)
        #pragma unroll
        for (int mt = 0; mt < 2; ++mt)
            #pragma unroll
            for (int t = 0; t < 2; ++t)
                acc[mt][t] = __builtin_amdgcn_mfma_f32_16x16x32_bf16(af[mt][ks], bfr[t][ks], acc[mt][t], 0, 0, 0);
    #pragma unroll
    for (int mt = 0; mt < 2; ++mt)
        #pragma unroll
        for (int t = 0; t < 2; ++t)
            #pragma unroll
            for (int j = 0; j < 4; ++j) {
                int b = mt * 16 + q * 4 + j;
                int n = (wid * 2 + t) * 16 + r;
                G[(((size_t)b * NKX + kxi) * 16 + ky) * 128 + n] = f2bf(acc[mt][t][j]);
            }
}

// ---------------- kD: inverse DFT over kx as GEMM [128 x 64] @ [64 x 128] per (b,ky) ----------------
__global__ __launch_bounds__(256) void kD(const unsigned short* __restrict__ G, unsigned short* __restrict__ Z) {
    __shared__ float2 tw[128];
    __shared__ short Af[8 * 2 * 64 * 8];   // 16 KB  [mt][ks][lane][8]
    int tid = threadIdx.x;
    if (tid < 128) {
        float s, c;
        sincosf(TWOPI * (float)tid * (1.0f / 128.0f), &s, &c);
        tw[tid] = make_float2(c, s);
    }
    __syncthreads();
    // A[row=h][k=2kxi+ri]: ri0 -> cos(+theta), ri1 -> -sin(+theta)
    #pragma unroll
    for (int s = 0; s < 4; ++s) {
        int slot = tid + s * 256;          // 1024 slots
        int l = slot & 63, ks = (slot >> 6) & 1, mt = slot >> 7;
        int q = l >> 4, r = l & 15;
        int h = mt * 16 + r;
        int k0 = ks * 32 + q * 8;
        short v[8];
        #pragma unroll
        for (int e = 0; e < 8; ++e) {
            int k = k0 + e;
            int kxi = k >> 1, ri = k & 1;
            int kx = (kxi < 16) ? kxi : (96 + kxi);
            float2 t = tw[(kx * h) & 127];
            v[e] = (short)f2bf(ri == 0 ? t.x : -t.y);
        }
        *(bf16x8*)&Af[slot * 8] = *(const bf16x8*)v;
    }
    __syncthreads();

    int blk = blockIdx.x;                  // b*16 + ky
    int b = blk >> 4, ky = blk & 15;
    int lane = tid & 63, wid = tid >> 6;
    int q = lane >> 4, r = lane & 15;
    // B[k=2kxi+ri][n=2c+ro] = G[..][n ^ ri], negated iff ri&ro
    bf16x8 bfr[2][2];
    #pragma unroll
    for (int t = 0; t < 2; ++t) {
        int n = (wid * 2 + t) * 16 + r;
        #pragma unroll
        for (int ks = 0; ks < 2; ++ks) {
            short v[8];
            #pragma unroll
            for (int e = 0; e < 8; ++e) {
                int k = ks * 32 + q * 8 + e;
                int kxi = k >> 1, ri = k & 1;
                unsigned short raw = G[(((size_t)b * NKX + kxi) * 16 + ky) * 128 + (n ^ ri)];
                if (ri & (n & 1)) raw ^= 0x8000u;
                v[e] = (short)raw;
            }
            bfr[t][ks] = *(const bf16x8*)v;
        }
    }
    f32x4 acc[8][2];
    #pragma unroll
    for (int mt = 0; mt < 8; ++mt)
        #pragma unroll
        for (int t = 0; t < 2; ++t)
            acc[mt][t] = (f32x4){0.f, 0.f, 0.f, 0.f};
    #pragma unroll
    for (int ks = 0; ks < 2; ++ks)
        #pragma unroll
        for (int mt = 0; mt < 8; ++mt) {
            bf16x8 a = *(const bf16x8*)&Af[((mt * 2 + ks) * 64 + lane) * 8];
            #pragma unroll
            for (int t = 0; t < 2; ++t)
                acc[mt][t] = __builtin_amdgcn_mfma_f32_16x16x32_bf16(a, bfr[t][ks], acc[mt][t], 0, 0, 0);
        }
    #pragma unroll
    for (int mt = 0; mt < 8; ++mt)
        #pragma unroll
        for (int t = 0; t < 2; ++t)
            #pragma unroll
            for (int j = 0; j < 4; ++j) {
                int h = mt * 16 + q * 4 + j;
                int n = (wid * 2 + t) * 16 + r;
                Z[(((size_t)b * HH + h) * 16 + ky) * 128 + n] = f2bf(acc[mt][t][j]);
            }
}

// ---------------- kE: MFMA GEMM  out = GELU(x + [x|T]@[K;Z] + bias) ----------------
__global__ __launch_bounds__(256, 2) void kE(const float* __restrict__ x, const unsigned short* __restrict__ Zb,
                                             const float* __restrict__ K, const float* __restrict__ bias,
                                             float* __restrict__ out) {
    __shared__ float xs[WW * CC];               // 32 KB
    __shared__ short Afrag[8 * 3 * 64 * 8];     // 24 KB
    __shared__ short Bfrag[4 * 3 * 64 * 8];     // 12 KB
    __shared__ float2 tw[128];
    int tid = threadIdx.x;
    int bh = blockIdx.x;
    if (tid < 128) {
        float s, c;
        sincosf(TWOPI * (float)tid * (1.0f / 128.0f), &s, &c);
        tw[tid] = make_float2(c, s);
    }
    const float* xp = x + (size_t)bh * (WW * CC);
    for (int i = tid * 4; i < WW * CC; i += 1024)
        *(float4*)&xs[i] = *(const float4*)&xp[i];
    __syncthreads();

    const float inv = 1.0f / 16384.0f;
    #pragma unroll
    for (int s = 0; s < 6; ++s) {
        int slot = tid + s * 256;
        int l = slot & 63;
        int ks = (slot >> 6) % 3;
        int tm = slot / 192;
        int q = l >> 4, r = l & 15;
        int row = tm * 16 + r;
        short v[8];
        if (ks < 2) {
            int k0 = ks * 32 + q * 8;
            #pragma unroll
            for (int e = 0; e < 8; ++e) v[e] = (short)f2bf(xs[row * CC + k0 + e]);
        } else {
            #pragma unroll
            for (int e = 0; e < 8; ++e) {
                int ky = 4 * q + (e >> 1);
                float sc = ((ky == 0) ? 1.0f : 2.0f) * inv;
                float2 t = tw[(ky * row) & 127];
                float val = (e & 1) ? (-t.y * sc) : (t.x * sc);
                v[e] = (short)f2bf(val);
            }
        }
        *(bf16x8*)&Afrag[slot * 8] = *(const bf16x8*)v;
    }
    #pragma unroll
    for (int s = 0; s < 3; ++s) {
        int slot = tid + s * 256;
        int l = slot & 63;
        int ks = (slot >> 6) % 3;
        int nt = slot / 192;
        int q = l >> 4, r = l & 15;
        int col = nt * 16 + r;
        short v[8];
        if (ks < 2) {
            #pragma unroll
            for (int e = 0; e < 8; ++e) {
                int k = ks * 32 + q * 8 + e;
                v[e] = (short)f2bf(K[k * CC + col]);
            }
        } else {
            #pragma unroll
            for (int e = 0; e < 8; ++e) {
                int kp = q * 8 + e;
                v[e] = (short)Zb[(size_t)bh * 2048 + (kp >> 1) * 128 + 2 * col + (kp & 1)];
            }
        }
        *(bf16x8*)&Bfrag[slot * 8] = *(const bf16x8*)v;
    }
    __syncthreads();

    int lane = tid & 63;
    int wv = tid >> 6;
    int q = lane >> 4, r = lane & 15;
    #pragma unroll
    for (int nt = 0; nt < 4; ++nt) {
        #pragma unroll
        for (int t2 = 0; t2 < 2; ++t2) {
            int tm = wv * 2 + t2;
            f32x4 acc = {0.f, 0.f, 0.f, 0.f};
            #pragma unroll
            for (int ks = 0; ks < 3; ++ks) {
                bf16x8 a = *(const bf16x8*)&Afrag[((tm * 3 + ks) * 64 + lane) * 8];
                bf16x8 b = *(const bf16x8*)&Bfrag[((nt * 3 + ks) * 64 + lane) * 8];
                acc = __builtin_amdgcn_mfma_f32_16x16x32_bf16(a, b, acc, 0, 0, 0);
            }
            int c = nt * 16 + r;
            float bsv = bias[c];
            #pragma unroll
            for (int j = 0; j < 4; ++j) {
                int w = tm * 16 + q * 4 + j;
                float u = acc[j] + xs[w * CC + c] + bsv;
                float t = u + 0.044715f * u * u * u;
                float e = __expf(-1.5957691216057308f * t);
                out[(size_t)bh * (WW * CC) + w * CC + c] = u / (1.0f + e);
            }
        }
    }
}

extern "C" void kernel_launch(void* const* d_in, const int* in_sizes, int n_in,
                              void* d_out, int out_size, void* d_ws, size_t ws_size,
                              hipStream_t stream) {
    const float* x   = (const float*)d_in[0];
    const float* w1r = (const float*)d_in[1];
    const float* w1i = (const float*)d_in[2];
    const float* w2r = (const float*)d_in[3];
    const float* w2i = (const float*)d_in[4];
    const float* dk  = (const float*)d_in[5];
    const float* db  = (const float*)d_in[6];
    float* out = (float*)d_out;

    unsigned short* X1 = (unsigned short*)d_ws;      // 8,388,608 elems
    unsigned short* X2 = X1 + 8388608;               // 2,097,152 elems
    unsigned short* G  = X2 + 2097152;               // 2,097,152 elems
    unsigned short* Z  = G  + 2097152;               // 8,388,608 elems

    kA<<<BB * HH, 256, 0, stream>>>(x, X1);
    kB<<<BB * MY, 256, 0, stream>>>(X1, X2);
    kC<<<NKX * MY, 256, 0, stream>>>(w1r, w1i, w2r, w2i, X2, G);
    kD<<<BB * MY, 256, 0, stream>>>(G, Z);
    kE<<<BB * HH, 256, 0, stream>>>(x, Z, dk, db, out);
}